// Round 1
// baseline (300.092 us; speedup 1.0000x reference)
//
#include <hip/hip_runtime.h>
#include <hip/hip_bf16.h>

typedef unsigned short u16;
typedef __attribute__((ext_vector_type(8))) short bf16x8;
typedef __attribute__((ext_vector_type(4))) float f32x4;

#define L_SEQ 2048
#define BATCH 2
#define HID 1024
#define NH 16
#define HD 64
#define NC 32            // chunks of 64 along L
#define MTOK 4096        // B*L
#define GEPS 1e-5f
#define QSCALE 0.125f    // D^-0.5

__device__ __forceinline__ float bf2f(u16 u){
  union { unsigned int i; float f; } c; c.i = ((unsigned int)u) << 16; return c.f;
}
__device__ __forceinline__ u16 f2bf(float f){
  union { __hip_bfloat16 h; u16 u; } c; c.h = __float2bfloat16(f); return c.u;
}
__device__ __forceinline__ void unpack8(const u16* p, float* o){
  uint4 r = *(const uint4*)p;
  const u16* u = (const u16*)&r;
  #pragma unroll
  for (int e = 0; e < 8; e++) o[e] = bf2f(u[e]);
}

// ---------------- f32 -> bf16 convert (x) ----------------
__global__ __launch_bounds__(256) void gla_cvt_bf16(const float* __restrict__ in,
                                                    u16* __restrict__ out, int n){
  int i = (blockIdx.x * 256 + threadIdx.x) * 4;
  if (i >= n) return;
  float4 v = *(const float4*)&in[i];
  u16 o[4] = { f2bf(v.x), f2bf(v.y), f2bf(v.z), f2bf(v.w) };
  *(uint2*)&out[i] = *(uint2*)o;
}

// ---------------- W (K x N f32) -> WT (N x K bf16) ----------------
__global__ __launch_bounds__(256) void gla_transpose_bf16(const float* __restrict__ W,
                                                          u16* __restrict__ WT){
  __shared__ float tile[32][33];
  int tx = threadIdx.x & 31, ty = threadIdx.x >> 5;
  int n0 = blockIdx.x * 32, k0 = blockIdx.y * 32;
  #pragma unroll
  for (int r = ty; r < 32; r += 8)
    tile[r][tx] = W[(size_t)(k0 + r) * HID + n0 + tx];
  __syncthreads();
  #pragma unroll
  for (int r = ty; r < 32; r += 8)
    WT[(size_t)(n0 + r) * HID + k0 + tx] = f2bf(tile[tx][r]);
}

// ---------------- GEMM: A(MxK bf16) @ Bt(NxK bf16)^T -> C(MxN) ----------------
__device__ __forceinline__ void storeC(float* C, size_t i, float v){ C[i] = v; }
__device__ __forceinline__ void storeC(u16*   C, size_t i, float v){ C[i] = f2bf(v); }

template<typename OutT>
__global__ __launch_bounds__(256) void gla_gemm_bt(const u16* __restrict__ A,
                                                   const u16* __restrict__ Bt,
                                                   OutT* __restrict__ C,
                                                   int M, int N, int K){
  __shared__ u16 As[128 * 40];   // 80B rows: 16B-aligned, 2-way bank alias (free)
  __shared__ u16 Bs[128 * 40];
  const int tid = threadIdx.x;
  const int lane = tid & 63, wid = tid >> 6;
  const int wm = wid >> 1, wn = wid & 1;
  const int lr = lane & 15, lk = lane >> 4;
  const int bm = blockIdx.x, bn = blockIdx.y;
  const int grow = tid >> 2, gk8 = (tid & 3) * 8;
  const u16* Ag = A + (size_t)bm * 128 * K + (size_t)grow * K + gk8;
  const u16* Bg = Bt + (size_t)bn * 128 * K + (size_t)grow * K + gk8;

  f32x4 acc[4][4];
  #pragma unroll
  for (int i = 0; i < 4; i++)
    #pragma unroll
    for (int j = 0; j < 4; j++)
      #pragma unroll
      for (int e = 0; e < 4; e++) acc[i][j][e] = 0.f;

  for (int k0 = 0; k0 < K; k0 += 32){
    uint4 a0 = *(const uint4*)(Ag + k0);
    uint4 a1 = *(const uint4*)(Ag + (size_t)64 * K + k0);
    uint4 b0 = *(const uint4*)(Bg + k0);
    uint4 b1 = *(const uint4*)(Bg + (size_t)64 * K + k0);
    __syncthreads();
    *(uint4*)&As[grow * 40 + gk8] = a0;
    *(uint4*)&As[(grow + 64) * 40 + gk8] = a1;
    *(uint4*)&Bs[grow * 40 + gk8] = b0;
    *(uint4*)&Bs[(grow + 64) * 40 + gk8] = b1;
    __syncthreads();
    bf16x8 af[4], bfr[4];
    #pragma unroll
    for (int i = 0; i < 4; i++)
      af[i] = *(const bf16x8*)&As[(wm * 64 + i * 16 + lr) * 40 + lk * 8];
    #pragma unroll
    for (int i = 0; i < 4; i++)
      bfr[i] = *(const bf16x8*)&Bs[(wn * 64 + i * 16 + lr) * 40 + lk * 8];
    #pragma unroll
    for (int i = 0; i < 4; i++)
      #pragma unroll
      for (int j = 0; j < 4; j++)
        acc[i][j] = __builtin_amdgcn_mfma_f32_16x16x32_bf16(af[i], bfr[j], acc[i][j], 0, 0, 0);
  }
  #pragma unroll
  for (int i = 0; i < 4; i++)
    #pragma unroll
    for (int j = 0; j < 4; j++){
      int row0 = bm * 128 + wm * 64 + i * 16 + lk * 4;
      int col  = bn * 128 + wn * 64 + j * 16 + lr;
      #pragma unroll
      for (int r = 0; r < 4; r++)
        storeC(C, (size_t)(row0 + r) * N + col, acc[i][j][r]);
    }
}

// ---------------- low-rank gate: xg1 = x @ Wg1 (4096x1024 @ 1024x16) ----------------
__global__ __launch_bounds__(256) void gla_xg1(const float* __restrict__ x,
                                               const float* __restrict__ Wg1,
                                               float* __restrict__ xg1){
  int lane = threadIdx.x & 63, wid = threadIdx.x >> 6;
  int row = blockIdx.x * 4 + wid;
  const float* xr = x + (size_t)row * HID;
  float acc[16];
  #pragma unroll
  for (int n = 0; n < 16; n++) acc[n] = 0.f;
  for (int k = lane; k < HID; k += 64){
    float xv = xr[k];
    const float4* wr = (const float4*)(Wg1 + (size_t)k * 16);
    float4 w0 = wr[0], w1 = wr[1], w2 = wr[2], w3 = wr[3];
    acc[0]  += xv * w0.x; acc[1]  += xv * w0.y; acc[2]  += xv * w0.z; acc[3]  += xv * w0.w;
    acc[4]  += xv * w1.x; acc[5]  += xv * w1.y; acc[6]  += xv * w1.z; acc[7]  += xv * w1.w;
    acc[8]  += xv * w2.x; acc[9]  += xv * w2.y; acc[10] += xv * w2.z; acc[11] += xv * w2.w;
    acc[12] += xv * w3.x; acc[13] += xv * w3.y; acc[14] += xv * w3.z; acc[15] += xv * w3.w;
  }
  #pragma unroll
  for (int n = 0; n < 16; n++){
    #pragma unroll
    for (int off = 32; off > 0; off >>= 1)
      acc[n] += __shfl_down(acc[n], off, 64);
  }
  if (lane == 0){
    #pragma unroll
    for (int n = 0; n < 16; n++) xg1[(size_t)row * 16 + n] = acc[n];
  }
}

// ---------------- gk = log_sigmoid(xg1 @ Wg2 + bg2) / 16 ----------------
__global__ __launch_bounds__(256) void gla_gk(const float* __restrict__ xg1,
                                              const float* __restrict__ Wg2,
                                              const float* __restrict__ bg2,
                                              float* __restrict__ GK){
  int row = blockIdx.x;
  __shared__ float xr[16];
  if (threadIdx.x < 16) xr[threadIdx.x] = xg1[(size_t)row * 16 + threadIdx.x];
  __syncthreads();
  for (int hcol = threadIdx.x; hcol < HID; hcol += 256){
    float z = bg2[hcol];
    #pragma unroll
    for (int r = 0; r < 16; r++) z += xr[r] * Wg2[r * HID + hcol];
    float lsig = fminf(z, 0.f) - log1pf(expf(-fabsf(z)));
    GK[(size_t)row * HID + hcol] = lsig * (1.0f / 16.0f);
  }
}

// ---------------- pass B: per-chunk state contribution T_c = K^hat^T @ V ----------------
__global__ __launch_bounds__(256) void gla_chunk_state(const u16* __restrict__ Kb,
                                                       const u16* __restrict__ Vb,
                                                       const float* __restrict__ GK,
                                                       float* __restrict__ Tbuf,
                                                       float* __restrict__ Dbuf){
  __shared__ float cg[64 * 65];
  __shared__ float KH[64 * 65];
  __shared__ u16 VS16[64 * 64];
  int blk = blockIdx.x;
  int c = blk & (NC - 1), bh = blk >> 5;
  int b = bh >> 4, h = bh & 15;
  int tid = threadIdx.x;
  int tr = tid >> 2, tc = (tid & 3) * 16;
  size_t gbase = ((size_t)(b * L_SEQ + c * 64)) * HID + h * HD;

  const float* gkp = GK + gbase + (size_t)tr * HID + tc;
  #pragma unroll
  for (int j = 0; j < 16; j += 4){
    float4 v4 = *(const float4*)(gkp + j);
    cg[tr*65+tc+j+0] = v4.x; cg[tr*65+tc+j+1] = v4.y;
    cg[tr*65+tc+j+2] = v4.z; cg[tr*65+tc+j+3] = v4.w;
  }
  __syncthreads();
  if (tid < 64){
    float s = 0.f;
    for (int t = 0; t < 64; t++){ s += cg[t*65 + tid]; cg[t*65 + tid] = s; }
  }
  __syncthreads();
  {
    const u16* kp = Kb + gbase + (size_t)tr * HID + tc;
    const u16* vp = Vb + gbase + (size_t)tr * HID + tc;
    uint4 kr0 = *(const uint4*)(kp), kr1 = *(const uint4*)(kp + 8);
    uint4 vr0 = *(const uint4*)(vp), vr1 = *(const uint4*)(vp + 8);
    const u16* ku = (const u16*)&kr0; const u16* ku2 = (const u16*)&kr1;
    #pragma unroll
    for (int e = 0; e < 8; e++){
      int d = tc + e;
      KH[tr*65 + d] = bf2f(ku[e]) * expf(cg[63*65 + d] - cg[tr*65 + d]);
    }
    #pragma unroll
    for (int e = 0; e < 8; e++){
      int d = tc + 8 + e;
      KH[tr*65 + d] = bf2f(ku2[e]) * expf(cg[63*65 + d] - cg[tr*65 + d]);
    }
    *(uint4*)&VS16[tr*64 + tc] = vr0;
    *(uint4*)&VS16[tr*64 + tc + 8] = vr1;
  }
  __syncthreads();
  int d = tid & 63, v0 = (tid >> 6) * 16;
  float acc[16];
  #pragma unroll
  for (int v = 0; v < 16; v++) acc[v] = 0.f;
  for (int t = 0; t < 64; t++){
    float kv = KH[t*65 + d];       // lane-varying d, stride 65: conflict-free
    float vv[16];
    unpack8(&VS16[t*64 + v0], vv); // broadcast
    unpack8(&VS16[t*64 + v0 + 8], vv + 8);
    #pragma unroll
    for (int v = 0; v < 16; v++) acc[v] += kv * vv[v];
  }
  float* Tp = Tbuf + (size_t)blk * 4096 + d * 64 + v0;
  #pragma unroll
  for (int v = 0; v < 16; v += 4)
    *(float4*)(Tp + v) = make_float4(acc[v], acc[v+1], acc[v+2], acc[v+3]);
  if (tid < 64) Dbuf[(size_t)blk * 64 + tid] = expf(cg[63*65 + tid]);
}

// ---------------- pass C: sequential scan over chunk states (32 blocks) ----------------
// Overwrites Tbuf[slot c] with S_in (state entering chunk c); writes final state out.
__global__ __launch_bounds__(256) void gla_state_scan(float* __restrict__ Tbuf,
                                                      const float* __restrict__ Dbuf,
                                                      float* __restrict__ Sfin){
  int bh = blockIdx.x;
  int tid = threadIdx.x;
  int d = tid >> 2, v0 = (tid & 3) * 16;
  float S[16];
  #pragma unroll
  for (int i = 0; i < 16; i++) S[i] = 0.f;
  for (int c = 0; c < NC; c++){
    size_t slot = (size_t)bh * NC + c;
    float* Tp = Tbuf + slot * 4096 + (size_t)d * 64 + v0;
    float dec = Dbuf[slot * 64 + d];
    float t[16];
    #pragma unroll
    for (int i = 0; i < 16; i += 4){
      float4 x4 = *(const float4*)(Tp + i);
      t[i] = x4.x; t[i+1] = x4.y; t[i+2] = x4.z; t[i+3] = x4.w;
    }
    #pragma unroll
    for (int i = 0; i < 16; i += 4)
      *(float4*)(Tp + i) = make_float4(S[i], S[i+1], S[i+2], S[i+3]);
    #pragma unroll
    for (int i = 0; i < 16; i++) S[i] = dec * S[i] + t[i];
  }
  float* Fp = Sfin + (size_t)bh * 4096 + (size_t)d * 64 + v0;
  #pragma unroll
  for (int i = 0; i < 16; i += 4)
    *(float4*)(Fp + i) = make_float4(S[i], S[i+1], S[i+2], S[i+3]);
}

// ---------------- pass D: per-chunk outputs + RMSNorm + swish gate ----------------
__global__ __launch_bounds__(256) void gla_chunk_out(const u16* __restrict__ Qb,
                                                     const u16* __restrict__ Kb,
                                                     const u16* __restrict__ Vb,
                                                     const float* __restrict__ GK,
                                                     const float* __restrict__ Sbuf,
                                                     const u16* __restrict__ Gb,
                                                     const float* __restrict__ gnw,
                                                     u16* __restrict__ OG){
  __shared__ float cgP[64 * 65];     // cumsum(gk) then reused for P
  __shared__ u16   QT16[64 * 66];    // q~ bf16, stride 66 => 2-way alias (free)
  __shared__ float KT[64 * 65];      // k~ fp32
  __shared__ u16   VS16[64 * 64];
  __shared__ u16   SS16[64 * 64];
  __shared__ float red[4 * 64];
  int blk = blockIdx.x;
  int c = blk & (NC - 1), bh = blk >> 5;
  int b = bh >> 4, h = bh & 15;
  int tid = threadIdx.x;
  int tr = tid >> 2, tc = (tid & 3) * 16;
  size_t gbase = ((size_t)(b * L_SEQ + c * 64)) * HID + h * HD;

  const float* gkp = GK + gbase + (size_t)tr * HID + tc;
  #pragma unroll
  for (int j = 0; j < 16; j += 4){
    float4 v4 = *(const float4*)(gkp + j);
    cgP[tr*65+tc+j+0] = v4.x; cgP[tr*65+tc+j+1] = v4.y;
    cgP[tr*65+tc+j+2] = v4.z; cgP[tr*65+tc+j+3] = v4.w;
  }
  __syncthreads();
  if (tid < 64){
    float s = 0.f;
    for (int t = 0; t < 64; t++){ s += cgP[t*65 + tid]; cgP[t*65 + tid] = s; }
  }
  __syncthreads();
  {
    const u16* qp = Qb + gbase + (size_t)tr * HID + tc;
    const u16* kp = Kb + gbase + (size_t)tr * HID + tc;
    const u16* vp = Vb + gbase + (size_t)tr * HID + tc;
    uint4 qr0 = *(const uint4*)(qp), qr1 = *(const uint4*)(qp + 8);
    uint4 kr0 = *(const uint4*)(kp), kr1 = *(const uint4*)(kp + 8);
    uint4 vr0 = *(const uint4*)(vp), vr1 = *(const uint4*)(vp + 8);
    const u16* qu = (const u16*)&qr0; const u16* qu2 = (const u16*)&qr1;
    const u16* ku = (const u16*)&kr0; const u16* ku2 = (const u16*)&kr1;
    #pragma unroll
    for (int e = 0; e < 8; e++){
      int dd = tc + e;
      float cgv = cgP[tr*65 + dd];
      QT16[tr*66 + dd] = f2bf(bf2f(qu[e]) * expf(cgv) * QSCALE);
      KT[tr*65 + dd]   = bf2f(ku[e]) * expf(-cgv);
    }
    #pragma unroll
    for (int e = 0; e < 8; e++){
      int dd = tc + 8 + e;
      float cgv = cgP[tr*65 + dd];
      QT16[tr*66 + dd] = f2bf(bf2f(qu2[e]) * expf(cgv) * QSCALE);
      KT[tr*65 + dd]   = bf2f(ku2[e]) * expf(-cgv);
    }
    *(uint4*)&VS16[tr*64 + tc] = vr0;
    *(uint4*)&VS16[tr*64 + tc + 8] = vr1;
    const float* sp = Sbuf + (size_t)blk * 4096 + tr * 64 + tc;
    #pragma unroll
    for (int j = 0; j < 16; j += 4){
      float4 s4 = *(const float4*)(sp + j);
      SS16[tr*64+tc+j+0] = f2bf(s4.x); SS16[tr*64+tc+j+1] = f2bf(s4.y);
      SS16[tr*64+tc+j+2] = f2bf(s4.z); SS16[tr*64+tc+j+3] = f2bf(s4.w);
    }
  }
  __syncthreads();
  int t = tid & 63;
  {
    // stage 2: P[t][j] = q~_t . k~_j (j <= t), written into cgP (reuse)
    int j0 = (tid >> 6) * 16;
    float pacc[16];
    #pragma unroll
    for (int j = 0; j < 16; j++) pacc[j] = 0.f;
    for (int dd = 0; dd < 64; dd++){
      float qv = bf2f(QT16[t*66 + dd]);            // lane-varying t: 2-way alias, free
      #pragma unroll
      for (int j = 0; j < 16; j++) pacc[j] += qv * KT[(j0 + j)*65 + dd]; // broadcast
    }
    #pragma unroll
    for (int j = 0; j < 16; j++)
      cgP[t*65 + j0 + j] = (j0 + j <= t) ? pacc[j] : 0.f;
  }
  __syncthreads();
  {
    // stage 3: O[t][v] = sum_d q~ S + sum_j P V ; epilogue RMSNorm + swish
    int vg = tid >> 6, v0 = vg * 16;
    float o[16];
    #pragma unroll
    for (int v = 0; v < 16; v++) o[v] = 0.f;
    for (int dd = 0; dd < 64; dd++){
      float qv = bf2f(QT16[t*66 + dd]);
      float sv[16];
      unpack8(&SS16[dd*64 + v0], sv);
      unpack8(&SS16[dd*64 + v0 + 8], sv + 8);
      #pragma unroll
      for (int v = 0; v < 16; v++) o[v] += qv * sv[v];
    }
    for (int j = 0; j < 64; j++){
      float pv = cgP[t*65 + j];                    // lane-varying t: conflict-free
      float vv[16];
      unpack8(&VS16[j*64 + v0], vv);
      unpack8(&VS16[j*64 + v0 + 8], vv + 8);
      #pragma unroll
      for (int v = 0; v < 16; v++) o[v] += pv * vv[v];
    }
    float ssq = 0.f;
    #pragma unroll
    for (int v = 0; v < 16; v++) ssq += o[v] * o[v];
    red[vg * 64 + t] = ssq;
    __syncthreads();
    float tot = red[t] + red[64 + t] + red[128 + t] + red[192 + t];
    float rn = rsqrtf(tot * (1.0f / 64.0f) + GEPS);
    const u16* gp = Gb + gbase + (size_t)t * HID + v0;
    uint4 gr0 = *(const uint4*)gp, gr1 = *(const uint4*)(gp + 8);
    float gv[16];
    { const u16* gu = (const u16*)&gr0;
      #pragma unroll
      for (int e = 0; e < 8; e++) gv[e] = bf2f(gu[e]);
      const u16* gu2 = (const u16*)&gr1;
      #pragma unroll
      for (int e = 0; e < 8; e++) gv[8 + e] = bf2f(gu2[e]); }
    u16 outv[16] __attribute__((aligned(16)));
    #pragma unroll
    for (int v = 0; v < 16; v++){
      float on = o[v] * rn * gnw[v0 + v];
      float g = gv[v];
      float sw = g / (1.f + expf(-g));
      outv[v] = f2bf(on * sw);
    }
    u16* op = OG + gbase + (size_t)t * HID + v0;
    *(uint4*)(op)     = *(uint4*)&outv[0];
    *(uint4*)(op + 8) = *(uint4*)&outv[8];
  }
}

// ---------------- host launcher ----------------
extern "C" void kernel_launch(void* const* d_in, const int* in_sizes, int n_in,
                              void* d_out, int out_size, void* d_ws, size_t ws_size,
                              hipStream_t stream){
  (void)in_sizes; (void)n_in; (void)out_size;
  const float* x   = (const float*)d_in[0];
  const float* Wq  = (const float*)d_in[1];
  const float* Wk  = (const float*)d_in[2];
  const float* Wv  = (const float*)d_in[3];
  const float* Wg1 = (const float*)d_in[4];
  const float* Wg2 = (const float*)d_in[5];
  const float* bg2 = (const float*)d_in[6];
  const float* Wg  = (const float*)d_in[7];
  const float* gnw = (const float*)d_in[8];
  const float* Wo  = (const float*)d_in[9];
  float* out = (float*)d_out;

  char* ws = (char*)d_ws;
  size_t off = 0;
  auto alloc = [&](size_t bytes) -> char* {
    char* p = ws + off; off += (bytes + 255) & ~(size_t)255; return p;
  };
  u16* xb   = (u16*)alloc((size_t)MTOK * HID * 2);
  u16* WTq  = (u16*)alloc((size_t)HID * HID * 2);
  u16* WTk  = (u16*)alloc((size_t)HID * HID * 2);
  u16* WTv  = (u16*)alloc((size_t)HID * HID * 2);
  u16* WTg  = (u16*)alloc((size_t)HID * HID * 2);
  u16* WTo  = (u16*)alloc((size_t)HID * HID * 2);
  u16* Qb   = (u16*)alloc((size_t)MTOK * HID * 2);
  u16* Kb   = (u16*)alloc((size_t)MTOK * HID * 2);
  u16* Vb   = (u16*)alloc((size_t)MTOK * HID * 2);
  u16* Gb   = (u16*)alloc((size_t)MTOK * HID * 2);
  float* GKb  = (float*)alloc((size_t)MTOK * HID * 4);
  float* xg1b = (float*)alloc((size_t)MTOK * 16 * 4);
  float* Tbuf = (float*)alloc((size_t)1024 * 4096 * 4);  // also holds S_in after pass C
  float* Dbuf = (float*)alloc((size_t)1024 * 64 * 4);
  u16* OG   = (u16*)alloc((size_t)MTOK * HID * 2);
  if (off > ws_size) return;  // insufficient workspace; leave output poisoned

  gla_cvt_bf16<<<4096, 256, 0, stream>>>(x, xb, MTOK * HID);
  dim3 tg(32, 32);
  gla_transpose_bf16<<<tg, 256, 0, stream>>>(Wq, WTq);
  gla_transpose_bf16<<<tg, 256, 0, stream>>>(Wk, WTk);
  gla_transpose_bf16<<<tg, 256, 0, stream>>>(Wv, WTv);
  gla_transpose_bf16<<<tg, 256, 0, stream>>>(Wg, WTg);
  gla_transpose_bf16<<<tg, 256, 0, stream>>>(Wo, WTo);

  gla_xg1<<<1024, 256, 0, stream>>>(x, Wg1, xg1b);
  gla_gk<<<4096, 256, 0, stream>>>(xg1b, Wg2, bg2, GKb);

  dim3 gg(32, 8);
  gla_gemm_bt<u16><<<gg, 256, 0, stream>>>(xb, WTq, Qb, MTOK, HID, HID);
  gla_gemm_bt<u16><<<gg, 256, 0, stream>>>(xb, WTk, Kb, MTOK, HID, HID);
  gla_gemm_bt<u16><<<gg, 256, 0, stream>>>(xb, WTv, Vb, MTOK, HID, HID);
  gla_gemm_bt<u16><<<gg, 256, 0, stream>>>(xb, WTg, Gb, MTOK, HID, HID);

  gla_chunk_state<<<1024, 256, 0, stream>>>(Kb, Vb, GKb, Tbuf, Dbuf);
  gla_state_scan<<<32, 256, 0, stream>>>(Tbuf, Dbuf, out + (size_t)MTOK * HID);
  gla_chunk_out<<<1024, 256, 0, stream>>>(Qb, Kb, Vb, GKb, Tbuf, Gb, gnw, OG);

  gla_gemm_bt<float><<<gg, 256, 0, stream>>>(OG, WTo, out, MTOK, HID, HID);
}

// Round 2
// 167.644 us; speedup vs baseline: 1.7901x; 1.7901x over previous
//
#include <hip/hip_runtime.h>
#include <hip/hip_bf16.h>

typedef unsigned short u16;
typedef __attribute__((ext_vector_type(8))) short bf16x8;
typedef __attribute__((ext_vector_type(4))) float f32x4;

#define L_SEQ 2048
#define HID 1024
#define NC 32
#define MTOK 4096
#define GEPS 1e-5f
#define QSCALE 0.125f

__device__ __forceinline__ float bf2f(u16 u){ union{unsigned i; float f;}c; c.i=(unsigned)u<<16; return c.f; }
__device__ __forceinline__ u16 f2bf(float f){ union{__hip_bfloat16 h; u16 u;}c; c.h=__float2bfloat16(f); return c.u; }

__device__ __forceinline__ void gload_lds16(const u16* g, u16* l){
  __builtin_amdgcn_global_load_lds((const __attribute__((address_space(1))) void*)g,
                                   (__attribute__((address_space(3))) void*)l, 16, 0, 0);
}

// ---------------- f32 -> bf16 convert (x) ----------------
__global__ __launch_bounds__(256) void gla_cvt_bf16(const float* __restrict__ in,
                                                    u16* __restrict__ out, int n){
  int i = (blockIdx.x * 256 + threadIdx.x) * 4;
  if (i >= n) return;
  float4 v = *(const float4*)&in[i];
  u16 o[4] = { f2bf(v.x), f2bf(v.y), f2bf(v.z), f2bf(v.w) };
  *(uint2*)&out[i] = *(uint2*)o;
}

// ---------------- 5x W (KxN f32) -> WT (NxK bf16), batched over z ----------------
__global__ __launch_bounds__(256) void gla_transpose5(const float* W0, const float* W1,
                                                      const float* W2, const float* W3,
                                                      const float* W4,
                                                      u16* D0, u16* D1, u16* D2, u16* D3, u16* D4){
  const float* W; u16* D;
  switch (blockIdx.z){
    case 0: W = W0; D = D0; break;
    case 1: W = W1; D = D1; break;
    case 2: W = W2; D = D2; break;
    case 3: W = W3; D = D3; break;
    default: W = W4; D = D4; break;
  }
  __shared__ float tile[32][33];
  int tx = threadIdx.x & 31, ty = threadIdx.x >> 5;
  int n0 = blockIdx.x * 32, k0 = blockIdx.y * 32;
  #pragma unroll
  for (int r = ty; r < 32; r += 8)
    tile[r][tx] = W[(size_t)(k0 + r) * HID + n0 + tx];
  __syncthreads();
  #pragma unroll
  for (int r = ty; r < 32; r += 8)
    D[(size_t)(n0 + r) * HID + k0 + tx] = f2bf(tile[tx][r]);
}

// ---------------- GEMM (m97 structure): A(Mx1024 bf16) @ Bt(Nx1024)^T ----------------
__device__ __forceinline__ void storeC(float* C, size_t i, float v){ C[i] = v; }
__device__ __forceinline__ void storeC(u16*   C, size_t i, float v){ C[i] = f2bf(v); }

template<typename OutT>
__global__ __launch_bounds__(256) void gla_gemm2(const u16* __restrict__ A,
                                                 const u16* __restrict__ Bt,
                                                 OutT* __restrict__ C){
  __shared__ u16 As[128 * 32];
  __shared__ u16 Bs[128 * 32];
  const int tid = threadIdx.x;
  const int lane = tid & 63, wid = tid >> 6;
  const int wm = wid >> 1, wn = wid & 1;
  const int lr = lane & 15, lk = lane >> 4;
  const int bm = blockIdx.x, bn = blockIdx.y;
  // staging mapping: issue i covers rows i*64..i*64+63; thread t -> row (t>>2), k8 (t&3)*8
  const u16* Ag0 = A + ((size_t)bm * 128 + (tid >> 2)) * HID + (tid & 3) * 8;
  const u16* Bg0 = Bt + ((size_t)bn * 128 + (tid >> 2)) * HID + (tid & 3) * 8;
  const u16* Ag1 = Ag0 + (size_t)64 * HID;
  const u16* Bg1 = Bg0 + (size_t)64 * HID;
  u16* la0 = As + tid * 8;  u16* la1 = As + 2048 + tid * 8;
  u16* lb0 = Bs + tid * 8;  u16* lb1 = Bs + 2048 + tid * 8;

  f32x4 acc[4][4];
  #pragma unroll
  for (int i = 0; i < 4; i++)
    #pragma unroll
    for (int j = 0; j < 4; j++)
      #pragma unroll
      for (int e = 0; e < 4; e++) acc[i][j][e] = 0.f;

  for (int k0 = 0; k0 < HID; k0 += 32){
    __syncthreads();                 // prior iter's LDS reads complete
    gload_lds16(Ag0 + k0, la0);
    gload_lds16(Ag1 + k0, la1);
    gload_lds16(Bg0 + k0, lb0);
    gload_lds16(Bg1 + k0, lb1);
    __syncthreads();                 // drains vmcnt -> LDS data visible
    bf16x8 af[4], bfr[4];
    #pragma unroll
    for (int i = 0; i < 4; i++)
      af[i] = *(const bf16x8*)&As[(wm * 64 + i * 16 + lr) * 32 + lk * 8];
    #pragma unroll
    for (int j = 0; j < 4; j++)
      bfr[j] = *(const bf16x8*)&Bs[(wn * 64 + j * 16 + lr) * 32 + lk * 8];
    #pragma unroll
    for (int i = 0; i < 4; i++)
      #pragma unroll
      for (int j = 0; j < 4; j++)
        acc[i][j] = __builtin_amdgcn_mfma_f32_16x16x32_bf16(af[i], bfr[j], acc[i][j], 0, 0, 0);
  }
  #pragma unroll
  for (int i = 0; i < 4; i++)
    #pragma unroll
    for (int j = 0; j < 4; j++){
      int row0 = bm * 128 + wm * 64 + i * 16 + lk * 4;
      int cb   = bn * 128 + wn * 64 + j * 16 + lr;
      int sel  = cb >> 10, col = cb & 1023;
      size_t base = (size_t)sel * ((size_t)MTOK * HID) + (size_t)row0 * HID + col;
      #pragma unroll
      for (int r = 0; r < 4; r++)
        storeC(C, base + (size_t)r * HID, acc[i][j][r]);
    }
}

// ---------------- low-rank gate stage 1: xg1 = x @ Wg1 ----------------
__global__ __launch_bounds__(256) void gla_xg1(const float* __restrict__ x,
                                               const float* __restrict__ Wg1,
                                               float* __restrict__ xg1){
  int lane = threadIdx.x & 63, wid = threadIdx.x >> 6;
  int row = blockIdx.x * 4 + wid;
  const float* xr = x + (size_t)row * HID;
  float acc[16];
  #pragma unroll
  for (int n = 0; n < 16; n++) acc[n] = 0.f;
  for (int k = lane; k < HID; k += 64){
    float xv = xr[k];
    const float4* wr = (const float4*)(Wg1 + (size_t)k * 16);
    float4 w0 = wr[0], w1 = wr[1], w2 = wr[2], w3 = wr[3];
    acc[0]  += xv * w0.x; acc[1]  += xv * w0.y; acc[2]  += xv * w0.z; acc[3]  += xv * w0.w;
    acc[4]  += xv * w1.x; acc[5]  += xv * w1.y; acc[6]  += xv * w1.z; acc[7]  += xv * w1.w;
    acc[8]  += xv * w2.x; acc[9]  += xv * w2.y; acc[10] += xv * w2.z; acc[11] += xv * w2.w;
    acc[12] += xv * w3.x; acc[13] += xv * w3.y; acc[14] += xv * w3.z; acc[15] += xv * w3.w;
  }
  #pragma unroll
  for (int n = 0; n < 16; n++){
    #pragma unroll
    for (int off = 32; off > 0; off >>= 1)
      acc[n] += __shfl_down(acc[n], off, 64);
  }
  if (lane == 0){
    #pragma unroll
    for (int n = 0; n < 16; n++) xg1[(size_t)row * 16 + n] = acc[n];
  }
}

// ---------------- gate stage 2 + per-chunk cumsum: CG = cumsum_chunk(logsig/16) ----------------
// grid: B * NC * 4 = 256 blocks; thread owns one hid column for a 64-token chunk.
__global__ __launch_bounds__(256) void gla_gkcg(const float* __restrict__ xg1,
                                                const float* __restrict__ Wg2,
                                                const float* __restrict__ bg2,
                                                float* __restrict__ CG){
  __shared__ float xs[64][16];
  int blk = blockIdx.x;
  int b = blk >> 7, r7 = blk & 127;
  int c = r7 >> 2, q = r7 & 3;
  int col = q * 256 + threadIdx.x;
  int tok0 = b * L_SEQ + c * 64;
  {
    int row = threadIdx.x >> 2, e4 = (threadIdx.x & 3) * 4;
    *(float4*)&xs[row][e4] = *(const float4*)&xg1[(size_t)(tok0 + row) * 16 + e4];
  }
  __syncthreads();
  float w[16];
  #pragma unroll
  for (int r = 0; r < 16; r++) w[r] = Wg2[r * HID + col];
  float bz = bg2[col];
  float cum = 0.f;
  for (int t = 0; t < 64; t++){
    float z = bz;
    #pragma unroll
    for (int r = 0; r < 16; r++) z += xs[t][r] * w[r];
    float ls = fminf(z, 0.f) - log1pf(__expf(-fabsf(z)));
    cum += ls * (1.0f / 16.0f);
    CG[(size_t)(tok0 + t) * HID + col] = cum;
  }
}

// ---------------- pass B (MFMA): T_c = K^hat^T @ V, D_c = exp(cg_last) ----------------
__global__ __launch_bounds__(256) void gla_chunk_state2(const u16* __restrict__ Kb,
                                                        const u16* __restrict__ Vb,
                                                        const float* __restrict__ CG,
                                                        float* __restrict__ Tbuf,
                                                        float* __restrict__ Dbuf){
  __shared__ u16 KHT[64 * 72];   // K^hat transposed: rows d, k = t
  __shared__ u16 VT[64 * 72];    // V transposed: rows v, k = t
  int blk = blockIdx.x;
  int c = blk & (NC - 1), bh = blk >> 5;
  int b = bh >> 4, h = bh & 15;
  int tid = threadIdx.x;
  int lane = tid & 63, w = tid >> 6;
  int lr = lane & 15, lk = lane >> 4;
  int tr = tid >> 2, tc = (tid & 3) * 16;
  size_t gbase = ((size_t)(b * L_SEQ + c * 64)) * HID + h * 64;

  float cg[16], cgl[16];
  {
    const float* cgp = CG + gbase + (size_t)tr * HID + tc;
    const float* clp = CG + gbase + (size_t)63 * HID + tc;
    #pragma unroll
    for (int j = 0; j < 16; j += 4){
      float4 a4 = *(const float4*)(cgp + j);
      float4 l4 = *(const float4*)(clp + j);
      cg[j] = a4.x; cg[j+1] = a4.y; cg[j+2] = a4.z; cg[j+3] = a4.w;
      cgl[j] = l4.x; cgl[j+1] = l4.y; cgl[j+2] = l4.z; cgl[j+3] = l4.w;
    }
  }
  {
    const u16* kp = Kb + gbase + (size_t)tr * HID + tc;
    const u16* vp = Vb + gbase + (size_t)tr * HID + tc;
    uint4 kr0 = *(const uint4*)kp, kr1 = *(const uint4*)(kp + 8);
    uint4 vr0 = *(const uint4*)vp, vr1 = *(const uint4*)(vp + 8);
    const u16* ku = (const u16*)&kr0; const u16* ku2 = (const u16*)&kr1;
    const u16* vu = (const u16*)&vr0; const u16* vu2 = (const u16*)&vr1;
    #pragma unroll
    for (int e = 0; e < 8; e++){
      KHT[(tc + e) * 72 + tr]     = f2bf(bf2f(ku[e])  * __expf(cgl[e]     - cg[e]));
      KHT[(tc + 8 + e) * 72 + tr] = f2bf(bf2f(ku2[e]) * __expf(cgl[8 + e] - cg[8 + e]));
      VT[(tc + e) * 72 + tr]      = vu[e];
      VT[(tc + 8 + e) * 72 + tr]  = vu2[e];
    }
  }
  if (tr == 0){
    #pragma unroll
    for (int e = 0; e < 16; e++)
      Dbuf[(size_t)blk * 64 + tc + e] = __expf(cgl[e]);
  }
  __syncthreads();
  int R0 = w * 16;
  f32x4 tacc[4];
  #pragma unroll
  for (int v = 0; v < 4; v++)
    #pragma unroll
    for (int e = 0; e < 4; e++) tacc[v][e] = 0.f;
  #pragma unroll
  for (int ks = 0; ks < 2; ks++){
    bf16x8 a = *(const bf16x8*)&KHT[(R0 + lr) * 72 + ks * 32 + lk * 8];
    #pragma unroll
    for (int v0 = 0; v0 < 4; v0++){
      bf16x8 bb = *(const bf16x8*)&VT[(v0 * 16 + lr) * 72 + ks * 32 + lk * 8];
      tacc[v0] = __builtin_amdgcn_mfma_f32_16x16x32_bf16(a, bb, tacc[v0], 0, 0, 0);
    }
  }
  #pragma unroll
  for (int v0 = 0; v0 < 4; v0++){
    int d = R0 + lk * 4, v = v0 * 16 + lr;
    #pragma unroll
    for (int r = 0; r < 4; r++)
      Tbuf[(size_t)blk * 4096 + (size_t)(d + r) * 64 + v] = tacc[v0][r];
  }
}

// ---------------- pass C: parallel chunk-state scan (512 blocks) ----------------
__global__ __launch_bounds__(256) void gla_state_scan2(float* __restrict__ Tbuf,
                                                       const float* __restrict__ Dbuf,
                                                       float* __restrict__ Sfin){
  int bh = blockIdx.x >> 4, seg = blockIdx.x & 15;
  int dv = seg * 256 + threadIdx.x;
  int d = dv >> 6;
  float S = 0.f;
  for (int c = 0; c < NC; c++){
    size_t slot = (size_t)bh * NC + c;
    float t  = Tbuf[slot * 4096 + dv];
    float dec = Dbuf[slot * 64 + d];
    Tbuf[slot * 4096 + dv] = S;      // S_in for this chunk
    S = dec * S + t;
  }
  Sfin[(size_t)bh * 4096 + dv] = S;
}

// ---------------- pass D (MFMA): outputs + RMSNorm + swish gate ----------------
__global__ __launch_bounds__(256) void gla_chunk_out2(const u16* __restrict__ Qb,
                                                      const u16* __restrict__ Kb,
                                                      const u16* __restrict__ Vb,
                                                      const float* __restrict__ CG,
                                                      const float* __restrict__ Sbuf,
                                                      const u16* __restrict__ Gb,
                                                      const float* __restrict__ gnw,
                                                      u16* __restrict__ OG){
  __shared__ u16 QT[64 * 72];   // q~ rows t, k=d
  __shared__ u16 KT[64 * 72];   // k~ rows j, k=d ; reused for gate GS after matmul1
  __shared__ u16 VT[64 * 72];   // V^T rows v, k=t
  __shared__ u16 ST[64 * 72];   // S_in^T rows v, k=d ; reused for output staging
  __shared__ u16 PS[64 * 72];   // masked P rows t, k=j
  int blk = blockIdx.x;
  int c = blk & (NC - 1), bh = blk >> 5;
  int b = bh >> 4, h = bh & 15;
  int tid = threadIdx.x;
  int lane = tid & 63, w = tid >> 6;
  int lr = lane & 15, lk = lane >> 4;
  int tr = tid >> 2, tc = (tid & 3) * 16;
  size_t gbase = ((size_t)(b * L_SEQ + c * 64)) * HID + h * 64;

  // ---- stage q~, k~, V^T, S^T ----
  {
    float cg[16];
    const float* cgp = CG + gbase + (size_t)tr * HID + tc;
    #pragma unroll
    for (int j = 0; j < 16; j += 4){
      float4 a4 = *(const float4*)(cgp + j);
      cg[j] = a4.x; cg[j+1] = a4.y; cg[j+2] = a4.z; cg[j+3] = a4.w;
    }
    const u16* qp = Qb + gbase + (size_t)tr * HID + tc;
    const u16* kp = Kb + gbase + (size_t)tr * HID + tc;
    const u16* vp = Vb + gbase + (size_t)tr * HID + tc;
    uint4 qr0 = *(const uint4*)qp, qr1 = *(const uint4*)(qp + 8);
    uint4 kr0 = *(const uint4*)kp, kr1 = *(const uint4*)(kp + 8);
    uint4 vr0 = *(const uint4*)vp, vr1 = *(const uint4*)(vp + 8);
    const u16* qu = (const u16*)&qr0; const u16* qu2 = (const u16*)&qr1;
    const u16* ku = (const u16*)&kr0; const u16* ku2 = (const u16*)&kr1;
    const u16* vu = (const u16*)&vr0; const u16* vu2 = (const u16*)&vr1;
    u16 qt[16] __attribute__((aligned(16)));
    u16 kt[16] __attribute__((aligned(16)));
    #pragma unroll
    for (int e = 0; e < 8; e++){
      float ec0 = __expf(cg[e]),  ei0 = __expf(-cg[e]);
      float ec1 = __expf(cg[8+e]), ei1 = __expf(-cg[8+e]);
      qt[e]     = f2bf(bf2f(qu[e])  * ec0 * QSCALE);
      qt[8 + e] = f2bf(bf2f(qu2[e]) * ec1 * QSCALE);
      kt[e]     = f2bf(bf2f(ku[e])  * ei0);
      kt[8 + e] = f2bf(bf2f(ku2[e]) * ei1);
      VT[(tc + e) * 72 + tr]     = vu[e];
      VT[(tc + 8 + e) * 72 + tr] = vu2[e];
    }
    *(uint4*)&QT[tr * 72 + tc]     = *(uint4*)&qt[0];
    *(uint4*)&QT[tr * 72 + tc + 8] = *(uint4*)&qt[8];
    *(uint4*)&KT[tr * 72 + tc]     = *(uint4*)&kt[0];
    *(uint4*)&KT[tr * 72 + tc + 8] = *(uint4*)&kt[8];
    const float* sp = Sbuf + (size_t)blk * 4096 + (size_t)tr * 64 + tc;
    #pragma unroll
    for (int j = 0; j < 16; j += 4){
      float4 s4 = *(const float4*)(sp + j);
      ST[(tc + j + 0) * 72 + tr] = f2bf(s4.x);
      ST[(tc + j + 1) * 72 + tr] = f2bf(s4.y);
      ST[(tc + j + 2) * 72 + tr] = f2bf(s4.z);
      ST[(tc + j + 3) * 72 + tr] = f2bf(s4.w);
    }
  }
  __syncthreads();

  // ---- matmul 1: P = q~ @ k~^T, masked, -> PS (bf16) ----
  int R0 = w * 16;
  {
    f32x4 pacc[4];
    #pragma unroll
    for (int j = 0; j < 4; j++)
      #pragma unroll
      for (int e = 0; e < 4; e++) pacc[j][e] = 0.f;
    #pragma unroll
    for (int ks = 0; ks < 2; ks++){
      bf16x8 a = *(const bf16x8*)&QT[(R0 + lr) * 72 + ks * 32 + lk * 8];
      #pragma unroll
      for (int j0 = 0; j0 < 4; j0++){
        bf16x8 bb = *(const bf16x8*)&KT[(j0 * 16 + lr) * 72 + ks * 32 + lk * 8];
        pacc[j0] = __builtin_amdgcn_mfma_f32_16x16x32_bf16(a, bb, pacc[j0], 0, 0, 0);
      }
    }
    #pragma unroll
    for (int j0 = 0; j0 < 4; j0++){
      int j = j0 * 16 + lr;
      #pragma unroll
      for (int r = 0; r < 4; r++){
        int t = R0 + lk * 4 + r;
        PS[t * 72 + j] = (j <= t) ? f2bf(pacc[j0][r]) : (u16)0;
      }
    }
  }
  __syncthreads();

  // ---- stage gate into KT space; matmul 3 (q~ @ S^T) + matmul 2 (P @ V^T) ----
  uint4 gr0, gr1;
  {
    const u16* gp = Gb + gbase + (size_t)tr * HID + tc;
    gr0 = *(const uint4*)gp; gr1 = *(const uint4*)(gp + 8);
  }
  f32x4 oacc[4];
  #pragma unroll
  for (int v = 0; v < 4; v++)
    #pragma unroll
    for (int e = 0; e < 4; e++) oacc[v][e] = 0.f;
  #pragma unroll
  for (int ks = 0; ks < 2; ks++){
    bf16x8 a = *(const bf16x8*)&QT[(R0 + lr) * 72 + ks * 32 + lk * 8];
    #pragma unroll
    for (int v0 = 0; v0 < 4; v0++){
      bf16x8 bb = *(const bf16x8*)&ST[(v0 * 16 + lr) * 72 + ks * 32 + lk * 8];
      oacc[v0] = __builtin_amdgcn_mfma_f32_16x16x32_bf16(a, bb, oacc[v0], 0, 0, 0);
    }
  }
  #pragma unroll
  for (int ks = 0; ks < 2; ks++){
    bf16x8 a = *(const bf16x8*)&PS[(R0 + lr) * 72 + ks * 32 + lk * 8];
    #pragma unroll
    for (int v0 = 0; v0 < 4; v0++){
      bf16x8 bb = *(const bf16x8*)&VT[(v0 * 16 + lr) * 72 + ks * 32 + lk * 8];
      oacc[v0] = __builtin_amdgcn_mfma_f32_16x16x32_bf16(a, bb, oacc[v0], 0, 0, 0);
    }
  }
  *(uint4*)&KT[tr * 72 + tc]     = gr0;   // GS
  *(uint4*)&KT[tr * 72 + tc + 8] = gr1;
  __syncthreads();

  // ---- epilogue: RMSNorm over v, affine, swish gate; stage to ST then coalesced out ----
  {
    float gnv[4];
    #pragma unroll
    for (int v0 = 0; v0 < 4; v0++) gnv[v0] = gnw[v0 * 16 + lr];
    #pragma unroll
    for (int r = 0; r < 4; r++){
      float ssq = 0.f;
      #pragma unroll
      for (int v0 = 0; v0 < 4; v0++) ssq += oacc[v0][r] * oacc[v0][r];
      ssq += __shfl_xor(ssq, 1, 64);
      ssq += __shfl_xor(ssq, 2, 64);
      ssq += __shfl_xor(ssq, 4, 64);
      ssq += __shfl_xor(ssq, 8, 64);
      float rn = rsqrtf(ssq * (1.0f / 64.0f) + GEPS);
      int t = R0 + lk * 4 + r;
      #pragma unroll
      for (int v0 = 0; v0 < 4; v0++){
        float g = bf2f(KT[t * 72 + v0 * 16 + lr]);
        float sw = g / (1.f + __expf(-g));
        ST[t * 72 + v0 * 16 + lr] = f2bf(oacc[v0][r] * rn * gnv[v0] * sw);
      }
    }
  }
  __syncthreads();
  {
    uint4 o0 = *(uint4*)&ST[tr * 72 + tc];
    uint4 o1 = *(uint4*)&ST[tr * 72 + tc + 8];
    u16* op = OG + gbase + (size_t)tr * HID + tc;
    *(uint4*)op       = o0;
    *(uint4*)(op + 8) = o1;
  }
}

// ---------------- host launcher ----------------
extern "C" void kernel_launch(void* const* d_in, const int* in_sizes, int n_in,
                              void* d_out, int out_size, void* d_ws, size_t ws_size,
                              hipStream_t stream){
  (void)in_sizes; (void)n_in; (void)out_size;
  const float* x   = (const float*)d_in[0];
  const float* Wq  = (const float*)d_in[1];
  const float* Wk  = (const float*)d_in[2];
  const float* Wv  = (const float*)d_in[3];
  const float* Wg1 = (const float*)d_in[4];
  const float* Wg2 = (const float*)d_in[5];
  const float* bg2 = (const float*)d_in[6];
  const float* Wg  = (const float*)d_in[7];
  const float* gnw = (const float*)d_in[8];
  const float* Wo  = (const float*)d_in[9];
  float* out = (float*)d_out;

  char* ws = (char*)d_ws;
  size_t off = 0;
  auto alloc = [&](size_t bytes) -> char* {
    char* p = ws + off; off += (bytes + 255) & ~(size_t)255; return p;
  };
  u16* xb   = (u16*)alloc((size_t)MTOK * HID * 2);
  u16* WTq  = (u16*)alloc((size_t)HID * HID * 2);   // WTq..WTg contiguous: combined N=4096
  u16* WTk  = (u16*)alloc((size_t)HID * HID * 2);
  u16* WTv  = (u16*)alloc((size_t)HID * HID * 2);
  u16* WTg  = (u16*)alloc((size_t)HID * HID * 2);
  u16* WTo  = (u16*)alloc((size_t)HID * HID * 2);
  u16* Qb   = (u16*)alloc((size_t)MTOK * HID * 2);  // Qb..Gb contiguous: sel-strided C
  u16* Kb   = (u16*)alloc((size_t)MTOK * HID * 2);
  u16* Vb   = (u16*)alloc((size_t)MTOK * HID * 2);
  u16* Gb   = (u16*)alloc((size_t)MTOK * HID * 2);
  float* CGb  = (float*)alloc((size_t)MTOK * HID * 4);
  float* xg1b = (float*)alloc((size_t)MTOK * 16 * 4);
  float* Tbuf = (float*)alloc((size_t)1024 * 4096 * 4);  // T_c, then S_in after scan
  float* Dbuf = (float*)alloc((size_t)1024 * 64 * 4);
  u16* OG   = (u16*)alloc((size_t)MTOK * HID * 2);
  if (off > ws_size) return;

  gla_cvt_bf16<<<4096, 256, 0, stream>>>(x, xb, MTOK * HID);
  dim3 tg(32, 32, 5);
  gla_transpose5<<<tg, 256, 0, stream>>>(Wq, Wk, Wv, Wg, Wo, WTq, WTk, WTv, WTg, WTo);

  gla_xg1<<<1024, 256, 0, stream>>>(x, Wg1, xg1b);
  gla_gkcg<<<256, 256, 0, stream>>>(xg1b, Wg2, bg2, CGb);

  dim3 gq(32, 32);
  gla_gemm2<u16><<<gq, 256, 0, stream>>>(xb, WTq, Qb);   // Q,K,V,G in one dispatch

  gla_chunk_state2<<<1024, 256, 0, stream>>>(Kb, Vb, CGb, Tbuf, Dbuf);
  gla_state_scan2<<<512, 256, 0, stream>>>(Tbuf, Dbuf, out + (size_t)MTOK * HID);
  gla_chunk_out2<<<1024, 256, 0, stream>>>(Qb, Kb, Vb, CGb, Tbuf, Gb, gnw, OG);

  dim3 go(32, 8);
  gla_gemm2<float><<<go, 256, 0, stream>>>(OG, WTo, out);
}

// Round 3
// 149.708 us; speedup vs baseline: 2.0045x; 1.1198x over previous
//
#include <hip/hip_runtime.h>
#include <hip/hip_bf16.h>

typedef unsigned short u16;
typedef __attribute__((ext_vector_type(8))) short bf16x8;
typedef __attribute__((ext_vector_type(4))) float f32x4;

#define L_SEQ 2048
#define HID 1024
#define NC 32
#define MTOK 4096
#define GEPS 1e-5f
#define QSCALE 0.125f

__device__ __forceinline__ float bf2f(u16 u){ union{unsigned i; float f;}c; c.i=(unsigned)u<<16; return c.f; }
__device__ __forceinline__ u16 f2bf(float f){ union{__hip_bfloat16 h; u16 u;}c; c.h=__float2bfloat16(f); return c.u; }

__device__ __forceinline__ void gload_lds16(const u16* g, u16* l){
  __builtin_amdgcn_global_load_lds((const __attribute__((address_space(1))) void*)g,
                                   (__attribute__((address_space(3))) void*)l, 16, 0, 0);
}

// ---------------- 5x W (KxN f32) -> WT (NxK bf16), batched over z ----------------
__global__ __launch_bounds__(256) void gla_transpose5(const float* W0, const float* W1,
                                                      const float* W2, const float* W3,
                                                      const float* W4,
                                                      u16* D0, u16* D1, u16* D2, u16* D3, u16* D4){
  const float* W; u16* D;
  switch (blockIdx.z){
    case 0: W = W0; D = D0; break;
    case 1: W = W1; D = D1; break;
    case 2: W = W2; D = D2; break;
    case 3: W = W3; D = D3; break;
    default: W = W4; D = D4; break;
  }
  __shared__ float tile[32][33];
  int tx = threadIdx.x & 31, ty = threadIdx.x >> 5;
  int n0 = blockIdx.x * 32, k0 = blockIdx.y * 32;
  #pragma unroll
  for (int r = ty; r < 32; r += 8)
    tile[r][tx] = W[(size_t)(k0 + r) * HID + n0 + tx];
  __syncthreads();
  #pragma unroll
  for (int r = ty; r < 32; r += 8)
    D[(size_t)(n0 + r) * HID + k0 + tx] = f2bf(tile[tx][r]);
}

// ---------------- fused: xg1 = x @ Wg1 AND xb = bf16(x) ----------------
__global__ __launch_bounds__(256) void gla_xg1(const float* __restrict__ x,
                                               const float* __restrict__ Wg1,
                                               float* __restrict__ xg1,
                                               u16* __restrict__ xb){
  int lane = threadIdx.x & 63, wid = threadIdx.x >> 6;
  int row = blockIdx.x * 4 + wid;
  const float* xr = x + (size_t)row * HID;
  u16* xbr = xb + (size_t)row * HID;
  float acc[16];
  #pragma unroll
  for (int n = 0; n < 16; n++) acc[n] = 0.f;
  for (int k = lane; k < HID; k += 64){
    float xv = xr[k];
    xbr[k] = f2bf(xv);
    const float4* wr = (const float4*)(Wg1 + (size_t)k * 16);
    float4 w0 = wr[0], w1 = wr[1], w2 = wr[2], w3 = wr[3];
    acc[0]  += xv * w0.x; acc[1]  += xv * w0.y; acc[2]  += xv * w0.z; acc[3]  += xv * w0.w;
    acc[4]  += xv * w1.x; acc[5]  += xv * w1.y; acc[6]  += xv * w1.z; acc[7]  += xv * w1.w;
    acc[8]  += xv * w2.x; acc[9]  += xv * w2.y; acc[10] += xv * w2.z; acc[11] += xv * w2.w;
    acc[12] += xv * w3.x; acc[13] += xv * w3.y; acc[14] += xv * w3.z; acc[15] += xv * w3.w;
  }
  #pragma unroll
  for (int n = 0; n < 16; n++){
    #pragma unroll
    for (int off = 32; off > 0; off >>= 1)
      acc[n] += __shfl_down(acc[n], off, 64);
  }
  if (lane == 0){
    #pragma unroll
    for (int n = 0; n < 16; n++) xg1[(size_t)row * 16 + n] = acc[n];
  }
}

// ---------------- GEMM 128x128 (m97 structure): QKVG fused, sel-strided C ----------------
template<typename OutT>
__global__ __launch_bounds__(256) void gla_gemm2(const u16* __restrict__ A,
                                                 const u16* __restrict__ Bt,
                                                 OutT* __restrict__ C){
  __shared__ u16 As[128 * 32];
  __shared__ u16 Bs[128 * 32];
  const int tid = threadIdx.x;
  const int lane = tid & 63, wid = tid >> 6;
  const int wm = wid >> 1, wn = wid & 1;
  const int lr = lane & 15, lk = lane >> 4;
  const int bm = blockIdx.x, bn = blockIdx.y;
  const u16* Ag0 = A + ((size_t)bm * 128 + (tid >> 2)) * HID + (tid & 3) * 8;
  const u16* Bg0 = Bt + ((size_t)bn * 128 + (tid >> 2)) * HID + (tid & 3) * 8;
  const u16* Ag1 = Ag0 + (size_t)64 * HID;
  const u16* Bg1 = Bg0 + (size_t)64 * HID;
  u16* la0 = As + tid * 8;  u16* la1 = As + 2048 + tid * 8;
  u16* lb0 = Bs + tid * 8;  u16* lb1 = Bs + 2048 + tid * 8;

  f32x4 acc[4][4];
  #pragma unroll
  for (int i = 0; i < 4; i++)
    #pragma unroll
    for (int j = 0; j < 4; j++)
      #pragma unroll
      for (int e = 0; e < 4; e++) acc[i][j][e] = 0.f;

  for (int k0 = 0; k0 < HID; k0 += 32){
    __syncthreads();
    gload_lds16(Ag0 + k0, la0);
    gload_lds16(Ag1 + k0, la1);
    gload_lds16(Bg0 + k0, lb0);
    gload_lds16(Bg1 + k0, lb1);
    __syncthreads();
    bf16x8 af[4], bfr[4];
    #pragma unroll
    for (int i = 0; i < 4; i++)
      af[i] = *(const bf16x8*)&As[(wm * 64 + i * 16 + lr) * 32 + lk * 8];
    #pragma unroll
    for (int j = 0; j < 4; j++)
      bfr[j] = *(const bf16x8*)&Bs[(wn * 64 + j * 16 + lr) * 32 + lk * 8];
    #pragma unroll
    for (int i = 0; i < 4; i++)
      #pragma unroll
      for (int j = 0; j < 4; j++)
        acc[i][j] = __builtin_amdgcn_mfma_f32_16x16x32_bf16(af[i], bfr[j], acc[i][j], 0, 0, 0);
  }
  #pragma unroll
  for (int i = 0; i < 4; i++)
    #pragma unroll
    for (int j = 0; j < 4; j++){
      int row0 = bm * 128 + wm * 64 + i * 16 + lk * 4;
      int cb   = bn * 128 + wn * 64 + j * 16 + lr;
      int sel  = cb >> 10, col = cb & 1023;
      size_t base = (size_t)sel * ((size_t)MTOK * HID) + (size_t)row0 * HID + col;
      #pragma unroll
      for (int r = 0; r < 4; r++)
        C[base + (size_t)r * HID] = f2bf(acc[i][j][r]);
    }
}

// ---------------- GEMM 128x64 tiles (512 blocks): OG @ WTo^T -> out (f32) ----------------
__global__ __launch_bounds__(256) void gla_gemm_out(const u16* __restrict__ A,
                                                    const u16* __restrict__ Bt,
                                                    float* __restrict__ C){
  __shared__ u16 As[128 * 32];
  __shared__ u16 Bs[64 * 32];
  const int tid = threadIdx.x;
  const int lane = tid & 63, wid = tid >> 6;
  const int wm = wid >> 1, wn = wid & 1;       // wave tile: 64 rows x 32 cols
  const int lr = lane & 15, lk = lane >> 4;
  const int bm = blockIdx.x, bn = blockIdx.y;
  const u16* Ag0 = A + ((size_t)bm * 128 + (tid >> 2)) * HID + (tid & 3) * 8;
  const u16* Ag1 = Ag0 + (size_t)64 * HID;
  const u16* Bg0 = Bt + ((size_t)bn * 64 + (tid >> 2)) * HID + (tid & 3) * 8;
  u16* la0 = As + tid * 8;  u16* la1 = As + 2048 + tid * 8;
  u16* lb0 = Bs + tid * 8;

  f32x4 acc[4][2];
  #pragma unroll
  for (int i = 0; i < 4; i++)
    #pragma unroll
    for (int j = 0; j < 2; j++)
      #pragma unroll
      for (int e = 0; e < 4; e++) acc[i][j][e] = 0.f;

  for (int k0 = 0; k0 < HID; k0 += 32){
    __syncthreads();
    gload_lds16(Ag0 + k0, la0);
    gload_lds16(Ag1 + k0, la1);
    gload_lds16(Bg0 + k0, lb0);
    __syncthreads();
    bf16x8 af[4], bfr[2];
    #pragma unroll
    for (int i = 0; i < 4; i++)
      af[i] = *(const bf16x8*)&As[(wm * 64 + i * 16 + lr) * 32 + lk * 8];
    #pragma unroll
    for (int j = 0; j < 2; j++)
      bfr[j] = *(const bf16x8*)&Bs[(wn * 32 + j * 16 + lr) * 32 + lk * 8];
    #pragma unroll
    for (int i = 0; i < 4; i++)
      #pragma unroll
      for (int j = 0; j < 2; j++)
        acc[i][j] = __builtin_amdgcn_mfma_f32_16x16x32_bf16(af[i], bfr[j], acc[i][j], 0, 0, 0);
  }
  #pragma unroll
  for (int i = 0; i < 4; i++)
    #pragma unroll
    for (int j = 0; j < 2; j++){
      int row0 = bm * 128 + wm * 64 + i * 16 + lk * 4;
      int col  = bn * 64 + wn * 32 + j * 16 + lr;
      #pragma unroll
      for (int r = 0; r < 4; r++)
        C[(size_t)(row0 + r) * HID + col] = acc[i][j][r];
    }
}

// ======== fused per-chunk cumulative gate (computed in-block, bf16 in LDS) ========
// cgS: u16[64*72]; red: float[5][64] (red[4] = last-row cg, f32).
// Thread mapping: c64 = tid&63 (col within head), g = tid>>6 (token group of 16).
__device__ __forceinline__ void compute_cg(const float* __restrict__ xg1,
                                           const float* __restrict__ Wg2,
                                           const float* __restrict__ bg2,
                                           int tok0, int h, int tid,
                                           float (*xs)[16], float (*red)[64],
                                           u16* cgS, bool want_last){
  {
    int row = tid >> 2, e4 = (tid & 3) * 4;
    *(float4*)&xs[row][e4] = *(const float4*)&xg1[(size_t)(tok0 + row) * 16 + e4];
  }
  __syncthreads();
  int c64 = tid & 63, g = tid >> 6;
  int col = h * 64 + c64;
  float w[16];
  #pragma unroll
  for (int r = 0; r < 16; r++) w[r] = Wg2[r * HID + col];
  float bz = bg2[col];
  float pre[16];
  float cum = 0.f;
  #pragma unroll
  for (int i = 0; i < 16; i++){
    int t = g * 16 + i;
    float z = bz;
    #pragma unroll
    for (int r = 0; r < 16; r++) z += xs[t][r] * w[r];
    float ls = fminf(z, 0.f) - log1pf(__expf(-fabsf(z)));
    cum += ls * (1.0f / 16.0f);
    pre[i] = cum;
  }
  red[g][c64] = cum;
  __syncthreads();
  float offs = 0.f;
  #pragma unroll
  for (int gp = 0; gp < 3; gp++) if (gp < g) offs += red[gp][c64];
  #pragma unroll
  for (int i = 0; i < 16; i++)
    cgS[(g * 16 + i) * 72 + c64] = f2bf(offs + pre[i]);
  if (want_last && g == 0)
    red[4][c64] = red[0][c64] + red[1][c64] + red[2][c64] + red[3][c64];
  __syncthreads();
}

// ---------------- pass B (MFMA): T_c = K^hat^T @ V, D_c = exp(cg_last) ----------------
__global__ __launch_bounds__(256) void gla_chunk_state2(const u16* __restrict__ Kb,
                                                        const u16* __restrict__ Vb,
                                                        const float* __restrict__ xg1,
                                                        const float* __restrict__ Wg2,
                                                        const float* __restrict__ bg2,
                                                        float* __restrict__ Tbuf,
                                                        float* __restrict__ Dbuf){
  __shared__ float xs[64][16];
  __shared__ float red[5][64];
  __shared__ u16 cgS[64 * 72];
  __shared__ u16 KHT[64 * 72];   // K^hat transposed: rows d, k = t
  __shared__ u16 VT[64 * 72];    // V transposed: rows v, k = t
  int blk = blockIdx.x;
  int c = blk & (NC - 1), bh = blk >> 5;
  int b = bh >> 4, h = bh & 15;
  int tid = threadIdx.x;
  int lane = tid & 63, w = tid >> 6;
  int lr = lane & 15, lk = lane >> 4;
  int tr = tid >> 2, tc = (tid & 3) * 16;
  int tok0 = b * L_SEQ + c * 64;
  size_t gbase = (size_t)tok0 * HID + h * 64;

  compute_cg(xg1, Wg2, bg2, tok0, h, tid, xs, red, cgS, true);

  {
    float cg[16];
    uint4 c0 = *(uint4*)&cgS[tr * 72 + tc];
    uint4 c1 = *(uint4*)&cgS[tr * 72 + tc + 8];
    const u16* cu = (const u16*)&c0; const u16* cu2 = (const u16*)&c1;
    #pragma unroll
    for (int e = 0; e < 8; e++){ cg[e] = bf2f(cu[e]); cg[8 + e] = bf2f(cu2[e]); }
    const u16* kp = Kb + gbase + (size_t)tr * HID + tc;
    const u16* vp = Vb + gbase + (size_t)tr * HID + tc;
    uint4 kr0 = *(const uint4*)kp, kr1 = *(const uint4*)(kp + 8);
    uint4 vr0 = *(const uint4*)vp, vr1 = *(const uint4*)(vp + 8);
    const u16* ku = (const u16*)&kr0; const u16* ku2 = (const u16*)&kr1;
    const u16* vu = (const u16*)&vr0; const u16* vu2 = (const u16*)&vr1;
    #pragma unroll
    for (int e = 0; e < 8; e++){
      float cgl0 = red[4][tc + e], cgl1 = red[4][tc + 8 + e];
      KHT[(tc + e) * 72 + tr]     = f2bf(bf2f(ku[e])  * __expf(cgl0 - cg[e]));
      KHT[(tc + 8 + e) * 72 + tr] = f2bf(bf2f(ku2[e]) * __expf(cgl1 - cg[8 + e]));
      VT[(tc + e) * 72 + tr]      = vu[e];
      VT[(tc + 8 + e) * 72 + tr]  = vu2[e];
    }
  }
  if (tid < 64) Dbuf[(size_t)blk * 64 + tid] = __expf(red[4][tid]);
  __syncthreads();
  int R0 = w * 16;
  f32x4 tacc[4];
  #pragma unroll
  for (int v = 0; v < 4; v++)
    #pragma unroll
    for (int e = 0; e < 4; e++) tacc[v][e] = 0.f;
  #pragma unroll
  for (int ks = 0; ks < 2; ks++){
    bf16x8 a = *(const bf16x8*)&KHT[(R0 + lr) * 72 + ks * 32 + lk * 8];
    #pragma unroll
    for (int v0 = 0; v0 < 4; v0++){
      bf16x8 bb = *(const bf16x8*)&VT[(v0 * 16 + lr) * 72 + ks * 32 + lk * 8];
      tacc[v0] = __builtin_amdgcn_mfma_f32_16x16x32_bf16(a, bb, tacc[v0], 0, 0, 0);
    }
  }
  #pragma unroll
  for (int v0 = 0; v0 < 4; v0++){
    int d = R0 + lk * 4, v = v0 * 16 + lr;
    #pragma unroll
    for (int r = 0; r < 4; r++)
      Tbuf[(size_t)blk * 4096 + (size_t)(d + r) * 64 + v] = tacc[v0][r];
  }
}

// ---------------- pass C: parallel chunk-state scan (512 blocks) ----------------
__global__ __launch_bounds__(256) void gla_state_scan2(float* __restrict__ Tbuf,
                                                       const float* __restrict__ Dbuf,
                                                       float* __restrict__ Sfin){
  int bh = blockIdx.x >> 4, seg = blockIdx.x & 15;
  int dv = seg * 256 + threadIdx.x;
  int d = dv >> 6;
  float S = 0.f;
  for (int c = 0; c < NC; c++){
    size_t slot = (size_t)bh * NC + c;
    float t  = Tbuf[slot * 4096 + dv];
    float dec = Dbuf[slot * 64 + d];
    Tbuf[slot * 4096 + dv] = S;
    S = dec * S + t;
  }
  Sfin[(size_t)bh * 4096 + dv] = S;
}

// ---------------- pass D (MFMA): outputs + RMSNorm + swish gate ----------------
__global__ __launch_bounds__(256) void gla_chunk_out2(const u16* __restrict__ Qb,
                                                      const u16* __restrict__ Kb,
                                                      const u16* __restrict__ Vb,
                                                      const float* __restrict__ xg1,
                                                      const float* __restrict__ Wg2,
                                                      const float* __restrict__ bg2,
                                                      const float* __restrict__ Sbuf,
                                                      const u16* __restrict__ Gb,
                                                      const float* __restrict__ gnw,
                                                      u16* __restrict__ OG){
  __shared__ float xs[64][16];
  __shared__ float red[5][64];
  __shared__ u16 QT[64 * 72];   // q~ rows t, k=d
  __shared__ u16 KT[64 * 72];   // k~ rows j, k=d ; reused for gate after matmul1
  __shared__ u16 VT[64 * 72];   // V^T rows v, k=t
  __shared__ u16 ST[64 * 72];   // S_in^T rows v, k=d ; reused for output staging
  __shared__ u16 PS[64 * 72];   // cg (phase A) then masked P rows t, k=j
  int blk = blockIdx.x;
  int c = blk & (NC - 1), bh = blk >> 5;
  int b = bh >> 4, h = bh & 15;
  int tid = threadIdx.x;
  int lane = tid & 63, w = tid >> 6;
  int lr = lane & 15, lk = lane >> 4;
  int tr = tid >> 2, tc = (tid & 3) * 16;
  int tok0 = b * L_SEQ + c * 64;
  size_t gbase = (size_t)tok0 * HID + h * 64;

  compute_cg(xg1, Wg2, bg2, tok0, h, tid, xs, red, PS, false);

  // ---- stage q~, k~, V^T, S^T (cg read from PS, then PS is dead) ----
  {
    float cg[16];
    uint4 c0 = *(uint4*)&PS[tr * 72 + tc];
    uint4 c1 = *(uint4*)&PS[tr * 72 + tc + 8];
    const u16* cu = (const u16*)&c0; const u16* cu2 = (const u16*)&c1;
    #pragma unroll
    for (int e = 0; e < 8; e++){ cg[e] = bf2f(cu[e]); cg[8 + e] = bf2f(cu2[e]); }
    const u16* qp = Qb + gbase + (size_t)tr * HID + tc;
    const u16* kp = Kb + gbase + (size_t)tr * HID + tc;
    const u16* vp = Vb + gbase + (size_t)tr * HID + tc;
    uint4 qr0 = *(const uint4*)qp, qr1 = *(const uint4*)(qp + 8);
    uint4 kr0 = *(const uint4*)kp, kr1 = *(const uint4*)(kp + 8);
    uint4 vr0 = *(const uint4*)vp, vr1 = *(const uint4*)(vp + 8);
    const u16* qu = (const u16*)&qr0; const u16* qu2 = (const u16*)&qr1;
    const u16* ku = (const u16*)&kr0; const u16* ku2 = (const u16*)&kr1;
    const u16* vu = (const u16*)&vr0; const u16* vu2 = (const u16*)&vr1;
    u16 qt[16] __attribute__((aligned(16)));
    u16 kt[16] __attribute__((aligned(16)));
    #pragma unroll
    for (int e = 0; e < 8; e++){
      float ec0 = __expf(cg[e]),  ei0 = __expf(-cg[e]);
      float ec1 = __expf(cg[8+e]), ei1 = __expf(-cg[8+e]);
      qt[e]     = f2bf(bf2f(qu[e])  * ec0 * QSCALE);
      qt[8 + e] = f2bf(bf2f(qu2[e]) * ec1 * QSCALE);
      kt[e]     = f2bf(bf2f(ku[e])  * ei0);
      kt[8 + e] = f2bf(bf2f(ku2[e]) * ei1);
      VT[(tc + e) * 72 + tr]     = vu[e];
      VT[(tc + 8 + e) * 72 + tr] = vu2[e];
    }
    *(uint4*)&QT[tr * 72 + tc]     = *(uint4*)&qt[0];
    *(uint4*)&QT[tr * 72 + tc + 8] = *(uint4*)&qt[8];
    *(uint4*)&KT[tr * 72 + tc]     = *(uint4*)&kt[0];
    *(uint4*)&KT[tr * 72 + tc + 8] = *(uint4*)&kt[8];
    const float* sp = Sbuf + (size_t)blk * 4096 + (size_t)tr * 64 + tc;
    #pragma unroll
    for (int j = 0; j < 16; j += 4){
      float4 s4 = *(const float4*)(sp + j);
      ST[(tc + j + 0) * 72 + tr] = f2bf(s4.x);
      ST[(tc + j + 1) * 72 + tr] = f2bf(s4.y);
      ST[(tc + j + 2) * 72 + tr] = f2bf(s4.z);
      ST[(tc + j + 3) * 72 + tr] = f2bf(s4.w);
    }
  }
  __syncthreads();

  // ---- matmul 1: P = q~ @ k~^T, masked, -> PS (bf16) ----
  int R0 = w * 16;
  {
    f32x4 pacc[4];
    #pragma unroll
    for (int j = 0; j < 4; j++)
      #pragma unroll
      for (int e = 0; e < 4; e++) pacc[j][e] = 0.f;
    #pragma unroll
    for (int ks = 0; ks < 2; ks++){
      bf16x8 a = *(const bf16x8*)&QT[(R0 + lr) * 72 + ks * 32 + lk * 8];
      #pragma unroll
      for (int j0 = 0; j0 < 4; j0++){
        bf16x8 bb = *(const bf16x8*)&KT[(j0 * 16 + lr) * 72 + ks * 32 + lk * 8];
        pacc[j0] = __builtin_amdgcn_mfma_f32_16x16x32_bf16(a, bb, pacc[j0], 0, 0, 0);
      }
    }
    __syncthreads();   // cg reads done before PS overwrite (staging barrier above covers, this orders pacc->PS)
    #pragma unroll
    for (int j0 = 0; j0 < 4; j0++){
      int j = j0 * 16 + lr;
      #pragma unroll
      for (int r = 0; r < 4; r++){
        int t = R0 + lk * 4 + r;
        PS[t * 72 + j] = (j <= t) ? f2bf(pacc[j0][r]) : (u16)0;
      }
    }
  }
  __syncthreads();

  // ---- stage gate into KT space; matmul 3 (q~ @ S^T) + matmul 2 (P @ V^T) ----
  uint4 gr0, gr1;
  {
    const u16* gp = Gb + gbase + (size_t)tr * HID + tc;
    gr0 = *(const uint4*)gp; gr1 = *(const uint4*)(gp + 8);
  }
  f32x4 oacc[4];
  #pragma unroll
  for (int v = 0; v < 4; v++)
    #pragma unroll
    for (int e = 0; e < 4; e++) oacc[v][e] = 0.f;
  #pragma unroll
  for (int ks = 0; ks < 2; ks++){
    bf16x8 a = *(const bf16x8*)&QT[(R0 + lr) * 72 + ks * 32 + lk * 8];
    #pragma unroll
    for (int v0 = 0; v0 < 4; v0++){
      bf16x8 bb = *(const bf16x8*)&ST[(v0 * 16 + lr) * 72 + ks * 32 + lk * 8];
      oacc[v0] = __builtin_amdgcn_mfma_f32_16x16x32_bf16(a, bb, oacc[v0], 0, 0, 0);
    }
  }
  #pragma unroll
  for (int ks = 0; ks < 2; ks++){
    bf16x8 a = *(const bf16x8*)&PS[(R0 + lr) * 72 + ks * 32 + lk * 8];
    #pragma unroll
    for (int v0 = 0; v0 < 4; v0++){
      bf16x8 bb = *(const bf16x8*)&VT[(v0 * 16 + lr) * 72 + ks * 32 + lk * 8];
      oacc[v0] = __builtin_amdgcn_mfma_f32_16x16x32_bf16(a, bb, oacc[v0], 0, 0, 0);
    }
  }
  *(uint4*)&KT[tr * 72 + tc]     = gr0;   // gate
  *(uint4*)&KT[tr * 72 + tc + 8] = gr1;
  __syncthreads();

  // ---- epilogue: RMSNorm over v, affine, swish gate; stage to ST then coalesced out ----
  {
    float gnv[4];
    #pragma unroll
    for (int v0 = 0; v0 < 4; v0++) gnv[v0] = gnw[v0 * 16 + lr];
    #pragma unroll
    for (int r = 0; r < 4; r++){
      float ssq = 0.f;
      #pragma unroll
      for (int v0 = 0; v0 < 4; v0++) ssq += oacc[v0][r] * oacc[v0][r];
      ssq += __shfl_xor(ssq, 1, 64);
      ssq += __shfl_xor(ssq, 2, 64);
      ssq += __shfl_xor(ssq, 4, 64);
      ssq += __shfl_xor(ssq, 8, 64);
      float rn = rsqrtf(ssq * (1.0f / 64.0f) + GEPS);
      int t = R0 + lk * 4 + r;
      #pragma unroll
      for (int v0 = 0; v0 < 4; v0++){
        float g = bf2f(KT[t * 72 + v0 * 16 + lr]);
        float sw = g / (1.f + __expf(-g));
        ST[t * 72 + v0 * 16 + lr] = f2bf(oacc[v0][r] * rn * gnv[v0] * sw);
      }
    }
  }
  __syncthreads();
  {
    uint4 o0 = *(uint4*)&ST[tr * 72 + tc];
    uint4 o1 = *(uint4*)&ST[tr * 72 + tc + 8];
    u16* op = OG + gbase + (size_t)tr * HID + tc;
    *(uint4*)op       = o0;
    *(uint4*)(op + 8) = o1;
  }
}

// ---------------- host launcher ----------------
extern "C" void kernel_launch(void* const* d_in, const int* in_sizes, int n_in,
                              void* d_out, int out_size, void* d_ws, size_t ws_size,
                              hipStream_t stream){
  (void)in_sizes; (void)n_in; (void)out_size;
  const float* x   = (const float*)d_in[0];
  const float* Wq  = (const float*)d_in[1];
  const float* Wk  = (const float*)d_in[2];
  const float* Wv  = (const float*)d_in[3];
  const float* Wg1 = (const float*)d_in[4];
  const float* Wg2 = (const float*)d_in[5];
  const float* bg2 = (const float*)d_in[6];
  const float* Wg  = (const float*)d_in[7];
  const float* gnw = (const float*)d_in[8];
  const float* Wo  = (const float*)d_in[9];
  float* out = (float*)d_out;

  char* ws = (char*)d_ws;
  size_t off = 0;
  auto alloc = [&](size_t bytes) -> char* {
    char* p = ws + off; off += (bytes + 255) & ~(size_t)255; return p;
  };
  u16* xb   = (u16*)alloc((size_t)MTOK * HID * 2);
  u16* WTq  = (u16*)alloc((size_t)HID * HID * 2);   // WTq..WTg contiguous: combined N=4096
  u16* WTk  = (u16*)alloc((size_t)HID * HID * 2);
  u16* WTv  = (u16*)alloc((size_t)HID * HID * 2);
  u16* WTg  = (u16*)alloc((size_t)HID * HID * 2);
  u16* WTo  = (u16*)alloc((size_t)HID * HID * 2);
  u16* Qb   = (u16*)alloc((size_t)MTOK * HID * 2);  // Qb..Gb contiguous: sel-strided C
  u16* Kb   = (u16*)alloc((size_t)MTOK * HID * 2);
  u16* Vb   = (u16*)alloc((size_t)MTOK * HID * 2);
  u16* Gb   = (u16*)alloc((size_t)MTOK * HID * 2);
  float* xg1b = (float*)alloc((size_t)MTOK * 16 * 4);
  float* Tbuf = (float*)alloc((size_t)1024 * 4096 * 4);  // T_c, then S_in after scan
  float* Dbuf = (float*)alloc((size_t)1024 * 64 * 4);
  u16* OG   = (u16*)alloc((size_t)MTOK * HID * 2);
  if (off > ws_size) return;

  gla_xg1<<<1024, 256, 0, stream>>>(x, Wg1, xg1b, xb);
  dim3 tg(32, 32, 5);
  gla_transpose5<<<tg, 256, 0, stream>>>(Wq, Wk, Wv, Wg, Wo, WTq, WTk, WTv, WTg, WTo);

  dim3 gq(32, 32);
  gla_gemm2<u16><<<gq, 256, 0, stream>>>(xb, WTq, Qb);   // Q,K,V,G in one dispatch

  gla_chunk_state2<<<1024, 256, 0, stream>>>(Kb, Vb, xg1b, Wg2, bg2, Tbuf, Dbuf);
  gla_state_scan2<<<512, 256, 0, stream>>>(Tbuf, Dbuf, out + (size_t)MTOK * HID);
  gla_chunk_out2<<<1024, 256, 0, stream>>>(Qb, Kb, Vb, xg1b, Wg2, bg2, Tbuf, Gb, gnw, OG);

  dim3 go(32, 16);
  gla_gemm_out<<<go, 256, 0, stream>>>(OG, WTo, out);
}